// Round 10
// baseline (546.885 us; speedup 1.0000x reference)
//
#include <hip/hip_runtime.h>
#include <hip/hip_bf16.h>

#define B_ 4
#define S_ 2048
#define DM_ 512
#define H_ 4
#define DK_ 128
#define DI_ 1024
#define NV_ 5000

typedef __attribute__((ext_vector_type(8))) short bf16x8;
typedef __attribute__((ext_vector_type(8))) unsigned short u16x8;
typedef __attribute__((ext_vector_type(4))) unsigned short u16x4;
typedef __attribute__((ext_vector_type(4))) float f32x4;

__device__ inline unsigned short f2bf(float x) {
  unsigned int u = __float_as_uint(x);
  unsigned int r = (u + 0x7fffu + ((u >> 16) & 1u)) >> 16;
  return (unsigned short)r;
}

// ---------------- embed + temporal (f32 + bf16 outputs) ----------------
__global__ __launch_bounds__(256) void embed_kernel(
    const int* __restrict__ et, const int* __restrict__ vx,
    const float* __restrict__ tmv, const float* __restrict__ npm,
    const float* __restrict__ eemb, const float* __restrict__ vemb,
    float* __restrict__ enc0, unsigned short* __restrict__ enc0b) {
  int row = blockIdx.x;
  int t = et[row], v = vx[row];
  float time = tmv[row], mask = npm[row];
  int tid = threadIdx.x;
  #pragma unroll
  for (int k = 0; k < 2; ++k) {
    int dd = tid + k * 256;
    float pv = powf(10000.0f, (float)(dd & ~1) / 512.0f);
    float r = time / pv;
    float tem = (((dd & 1) == 0) ? sinf(r) : cosf(r)) * mask;
    float val = eemb[(size_t)t * DM_ + dd] + vemb[(size_t)v * DM_ + dd] + tem;
    enc0[(size_t)row * DM_ + dd] = val;
    enc0b[(size_t)row * DM_ + dd] = f2bf(val);
  }
}

// ---------------- similarity: stage A,W rows in LDS, gather ----------------
__global__ __launch_bounds__(256) void sim_kernel(
    const int* __restrict__ vx, const float* __restrict__ A,
    const float* __restrict__ W, float* __restrict__ sim) {
  __shared__ float Ar[NV_];
  __shared__ float Wr[NV_];
  int i = blockIdx.x;
  int b = blockIdx.y;
  int vi = vx[b * S_ + i];
  float* out = sim + ((size_t)(b * S_ + i)) * S_;
  int tid = threadIdx.x;
  if (vi == 0) {
    for (int j = tid * 4; j < S_; j += 1024)
      *(float4*)&out[j] = (float4){0.f, 0.f, 0.f, 0.f};
    return;
  }
  const float4* Arow = (const float4*)(A + (size_t)(vi - 1) * NV_);
  const float4* Wrow = (const float4*)(W + (size_t)(vi - 1) * NV_);
  for (int j = tid; j < NV_ / 4; j += 256) {
    ((float4*)Ar)[j] = Arow[j];
    ((float4*)Wr)[j] = Wrow[j];
  }
  __syncthreads();
  for (int j = tid * 4; j < S_; j += 1024) {
    int4 vj = *(const int4*)&vx[b * S_ + j];
    float4 o;
    o.x = vj.x ? Ar[vj.x - 1] * Wr[vj.x - 1] * 10.0f : 0.f;
    o.y = vj.y ? Ar[vj.y - 1] * Wr[vj.y - 1] * 10.0f : 0.f;
    o.z = vj.z ? Ar[vj.z - 1] * Wr[vj.z - 1] * 10.0f : 0.f;
    o.w = vj.w ? Ar[vj.w - 1] * Wr[vj.w - 1] * 10.0f : 0.f;
    *(float4*)&out[j] = o;
  }
}

// ---------------- weight transpose+cast: W[K][N] f32 -> WT[N][K] bf16 ----------------
__global__ __launch_bounds__(256) void wt_kernel(
    const float* __restrict__ W, unsigned short* __restrict__ WT,
    int K, int N) {
  __shared__ unsigned short T[32][40];
  int n0 = blockIdx.x * 32, k0 = blockIdx.y * 32;
  int r = threadIdx.x >> 3, c0 = (threadIdx.x & 7) * 4;
  float4 v = *(const float4*)&W[(size_t)(k0 + r) * N + n0 + c0];
  T[r][c0 + 0] = f2bf(v.x);
  T[r][c0 + 1] = f2bf(v.y);
  T[r][c0 + 2] = f2bf(v.z);
  T[r][c0 + 3] = f2bf(v.w);
  __syncthreads();
  u16x4 o;
  o[0] = T[c0 + 0][r]; o[1] = T[c0 + 1][r];
  o[2] = T[c0 + 2][r]; o[3] = T[c0 + 3][r];
  *(u16x4*)&WT[(size_t)(n0 + r) * K + k0 + c0] = o;
}

// ---------------- bf16 MFMA GEMM: C = A[M,K] @ BT[N,K]^T (+bias)(+relu) ----------------
// OMODE: 0 = f32 [M][N]; 1 = bf16 [M][N]; 2 = bf16 QK head-split; 3 = bf16 V-transposed
template <int OMODE, bool RELU>
__global__ __launch_bounds__(256) void gemm_bf16_kernel(
    const unsigned short* __restrict__ A, const unsigned short* __restrict__ BT,
    const float* __restrict__ bias, void* __restrict__ C,
    int M, int N, int K) {
  __shared__ __attribute__((aligned(16))) unsigned short As[128][72];
  __shared__ __attribute__((aligned(16))) unsigned short Bs[128][72];
  int tid = threadIdx.x;
  int w = tid >> 6, l = tid & 63;
  int l16 = l & 15, lh = l >> 4;
  int wr = w >> 1, wc = w & 1;
  int row0 = blockIdx.y * 128, col0 = blockIdx.x * 128;
  int ra = tid >> 1, ha = (tid & 1) * 32;
  f32x4 acc[4][4];
  #pragma unroll
  for (int m = 0; m < 4; ++m)
    #pragma unroll
    for (int n = 0; n < 4; ++n) acc[m][n] = (f32x4){0.f, 0.f, 0.f, 0.f};

  for (int k0 = 0; k0 < K; k0 += 64) {
    __syncthreads();
    {
      const unsigned short* sa = &A[(size_t)(row0 + ra) * K + k0 + ha];
      uint4 a0 = *(const uint4*)(sa);
      uint4 a1 = *(const uint4*)(sa + 8);
      uint4 a2 = *(const uint4*)(sa + 16);
      uint4 a3 = *(const uint4*)(sa + 24);
      *(uint4*)&As[ra][ha + 0] = a0;
      *(uint4*)&As[ra][ha + 8] = a1;
      *(uint4*)&As[ra][ha + 16] = a2;
      *(uint4*)&As[ra][ha + 24] = a3;
      const unsigned short* sb = &BT[(size_t)(col0 + ra) * K + k0 + ha];
      uint4 b0 = *(const uint4*)(sb);
      uint4 b1 = *(const uint4*)(sb + 8);
      uint4 b2 = *(const uint4*)(sb + 16);
      uint4 b3 = *(const uint4*)(sb + 24);
      *(uint4*)&Bs[ra][ha + 0] = b0;
      *(uint4*)&Bs[ra][ha + 8] = b1;
      *(uint4*)&Bs[ra][ha + 16] = b2;
      *(uint4*)&Bs[ra][ha + 24] = b3;
    }
    __syncthreads();
    #pragma unroll
    for (int kc = 0; kc < 2; ++kc) {
      bf16x8 af[4], bfr[4];
      #pragma unroll
      for (int m = 0; m < 4; ++m)
        af[m] = *(bf16x8*)&As[wr * 64 + m * 16 + l16][kc * 32 + lh * 8];
      #pragma unroll
      for (int n = 0; n < 4; ++n)
        bfr[n] = *(bf16x8*)&Bs[wc * 64 + n * 16 + l16][kc * 32 + lh * 8];
      #pragma unroll
      for (int m = 0; m < 4; ++m)
        #pragma unroll
        for (int n = 0; n < 4; ++n)
          acc[m][n] = __builtin_amdgcn_mfma_f32_16x16x32_bf16(af[m], bfr[n], acc[m][n], 0, 0, 0);
    }
  }
  #pragma unroll
  for (int m = 0; m < 4; ++m) {
    #pragma unroll
    for (int r = 0; r < 4; ++r) {
      int row = row0 + wr * 64 + m * 16 + lh * 4 + r;
      #pragma unroll
      for (int n = 0; n < 4; ++n) {
        int colg = col0 + wc * 64 + n * 16 + l16;
        float v = acc[m][n][r];
        if (bias) v += bias[colg];
        if (RELU) v = fmaxf(v, 0.f);
        if (OMODE == 0) {
          ((float*)C)[(size_t)row * N + colg] = v;
        } else if (OMODE == 1) {
          ((unsigned short*)C)[(size_t)row * N + colg] = f2bf(v);
        } else if (OMODE == 2) {
          int b = row >> 11, s = row & 2047;
          int h = colg >> 7, d = colg & 127;
          ((unsigned short*)C)[((size_t)((b * 4 + h) * 2048 + s)) * 128 + d] = f2bf(v);
        } else {
          int b = row >> 11, s = row & 2047;
          int h = colg >> 7, d = colg & 127;
          ((unsigned short*)C)[((size_t)((b * 4 + h) * 128 + d)) * 2048 + s] = f2bf(v);
        }
      }
    }
  }
}

// ---------------- MFMA flash attention: 2-wave blocks, paired 32-row q-tiles ----
// grid = (32 pairs, 16 bh); block = 128 (2 waves); exactly 33 kv-steps per block;
// double-buffered K/V (1 barrier/step); sim/npm register-prefetched.
__global__ __launch_bounds__(128) void attn_mfma_kernel(
    const unsigned short* __restrict__ Qb, const unsigned short* __restrict__ Kb,
    const unsigned short* __restrict__ Vt, const float* __restrict__ sim,
    const float* __restrict__ npm, unsigned short* __restrict__ O) {
  __shared__ __attribute__((aligned(16))) unsigned short Ks[2][64][136];
  __shared__ __attribute__((aligned(16))) unsigned short Vts[2][128][72];
  __shared__ __attribute__((aligned(16))) unsigned short Pl[2][16][72];
  int pair = blockIdx.x;   // 0..31
  int bh = blockIdx.y;     // b*H + h
  int b = bh >> 2;
  int h = bh & 3;
  int tid = threadIdx.x;
  int w = tid >> 6, l = tid & 63;
  int l16 = l & 15, lh = l >> 4;
  int kr = tid >> 4, kc = tid & 15;   // K staging: rows kr+8i (i=0..7)
  int vr = tid >> 3, vc = tid & 7;    // V staging: rows vr+16i (i=0..7)

  uint4 kg[8], vg[8];
  auto stage_load = [&](int kv0) {
    const unsigned short* kp = Kb + ((size_t)(bh * 2048 + kv0 + kr)) * 128 + kc * 8;
    #pragma unroll
    for (int i = 0; i < 8; ++i) kg[i] = *(const uint4*)(kp + i * 8 * 128);
    const unsigned short* vp = Vt + ((size_t)(bh * 128 + vr)) * 2048 + kv0 + vc * 8;
    #pragma unroll
    for (int i = 0; i < 8; ++i) vg[i] = *(const uint4*)(vp + i * 16 * 2048);
  };
  auto stage_write = [&](int bi) {
    #pragma unroll
    for (int i = 0; i < 8; ++i) *(uint4*)&Ks[bi][kr + i * 8][kc * 8] = kg[i];
    #pragma unroll
    for (int i = 0; i < 8; ++i) *(uint4*)&Vts[bi][vr + i * 16][vc * 8] = vg[i];
  };

  #pragma unroll 1
  for (int pi = 0; pi < 2; ++pi) {
    int qt = pi ? 63 - pair : pair;      // 32-row q tile index (0..63)
    int nst = (qt >> 1) + 1;             // kv-64 tiles needed (causal)
    int q0 = qt * 32 + w * 16;
    int qg = q0 + l16;                   // this lane's q row (swapped layout)

    bf16x8 qf[4];
    const unsigned short* Qrow = Qb + ((size_t)(bh * 2048 + qg)) * 128;
    #pragma unroll
    for (int kq = 0; kq < 4; ++kq)
      qf[kq] = *(const bf16x8*)&Qrow[kq * 32 + lh * 8];

    float m_l = -INFINITY, l_l = 0.f;
    f32x4 o_acc[8];
    #pragma unroll
    for (int c = 0; c < 8; ++c) o_acc[c] = (f32x4){0.f, 0.f, 0.f, 0.f};

    const float* simrow = sim + ((size_t)(b * 2048) + qg) * 2048;
    const float* mrow = npm + b * 2048;

    stage_load(0);
    stage_write(0);
    float4 simc[4], mkc[4];
    #pragma unroll
    for (int tt = 0; tt < 4; ++tt) {
      simc[tt] = *(const float4*)&simrow[tt * 16 + lh * 4];
      mkc[tt] = *(const float4*)&mrow[tt * 16 + lh * 4];
    }
    __syncthreads();

    #pragma unroll 1
    for (int t = 0; t < nst; ++t) {
      int cur = t & 1;
      int kv0 = t * 64;
      float4 simn[4], mkn[4];
      if (t + 1 < nst) {
        stage_load(kv0 + 64);
        #pragma unroll
        for (int tt = 0; tt < 4; ++tt) {
          simn[tt] = *(const float4*)&simrow[kv0 + 64 + tt * 16 + lh * 4];
          mkn[tt] = *(const float4*)&mrow[kv0 + 64 + tt * 16 + lh * 4];
        }
      }

      // swapped QK^T: C col = q (l16), row = kv (lh*4+r)
      f32x4 sc[4];
      #pragma unroll
      for (int tt = 0; tt < 4; ++tt) {
        sc[tt] = (f32x4){0.f, 0.f, 0.f, 0.f};
        #pragma unroll
        for (int kq = 0; kq < 4; ++kq) {
          bf16x8 kf = *(bf16x8*)&Ks[cur][tt * 16 + l16][kq * 32 + lh * 8];
          sc[tt] = __builtin_amdgcn_mfma_f32_16x16x32_bf16(kf, qf[kq], sc[tt], 0, 0, 0);
        }
      }
      float sv[4][4];
      #pragma unroll
      for (int tt = 0; tt < 4; ++tt) {
        #pragma unroll
        for (int r = 0; r < 4; ++r) {
          int kvg = kv0 + tt * 16 + lh * 4 + r;
          float mkr = ((const float*)&mkc[tt])[r];
          bool valid = (kvg <= qg) && (mkr != 0.f);
          sv[tt][r] = valid
              ? sc[tt][r] * 0.08838834764831845f + ((const float*)&simc[tt])[r]
              : -1e9f;
        }
      }
      // online softmax: lane owns full row slice; reduce in-lane + xor16/xor32
      float mx = sv[0][0];
      #pragma unroll
      for (int tt = 0; tt < 4; ++tt)
        #pragma unroll
        for (int r = 0; r < 4; ++r) mx = fmaxf(mx, sv[tt][r]);
      mx = fmaxf(mx, __shfl_xor(mx, 16));
      mx = fmaxf(mx, __shfl_xor(mx, 32));
      float mn = fmaxf(m_l, mx);
      float alpha = __expf(m_l - mn);
      m_l = mn;
      float ts = 0.f;
      #pragma unroll
      for (int tt = 0; tt < 4; ++tt)
        #pragma unroll
        for (int r = 0; r < 4; ++r) {
          float p = __expf(sv[tt][r] - mn);
          sv[tt][r] = p;
          ts += p;
        }
      ts += __shfl_xor(ts, 16);
      ts += __shfl_xor(ts, 32);
      l_l = l_l * alpha + ts;
      // P write: row q = l16, kv contiguous per tt -> ushort4
      #pragma unroll
      for (int tt = 0; tt < 4; ++tt) {
        u16x4 pw;
        pw[0] = f2bf(sv[tt][0]); pw[1] = f2bf(sv[tt][1]);
        pw[2] = f2bf(sv[tt][2]); pw[3] = f2bf(sv[tt][3]);
        *(u16x4*)&Pl[w][l16][tt * 16 + lh * 4] = pw;
      }
      // rescale O rows (q = lh*4+r): alpha from lane l16 = lh*4+r
      float al[4];
      #pragma unroll
      for (int r = 0; r < 4; ++r) al[r] = __shfl(alpha, lh * 4 + r);
      #pragma unroll
      for (int c = 0; c < 8; ++c)
        #pragma unroll
        for (int r = 0; r < 4; ++r) o_acc[c][r] *= al[r];
      // PV
      #pragma unroll
      for (int kf2 = 0; kf2 < 2; ++kf2) {
        bf16x8 pa = *(bf16x8*)&Pl[w][l16][kf2 * 32 + lh * 8];
        #pragma unroll
        for (int c = 0; c < 8; ++c) {
          bf16x8 vf = *(bf16x8*)&Vts[cur][c * 16 + l16][kf2 * 32 + lh * 8];
          o_acc[c] = __builtin_amdgcn_mfma_f32_16x16x32_bf16(pa, vf, o_acc[c], 0, 0, 0);
        }
      }
      if (t + 1 < nst) {
        stage_write((t + 1) & 1);
        #pragma unroll
        for (int tt = 0; tt < 4; ++tt) { simc[tt] = simn[tt]; mkc[tt] = mkn[tt]; }
      }
      __syncthreads();
    }
    // epilogue: O row q = q0 + lh*4 + r
    float linv[4];
    #pragma unroll
    for (int r = 0; r < 4; ++r) {
      float lv = __shfl(l_l, lh * 4 + r);
      linv[r] = 1.f / lv;
    }
    #pragma unroll
    for (int r = 0; r < 4; ++r) {
      int qgr = q0 + lh * 4 + r;
      unsigned short* op = O + ((size_t)(b * 2048 + qgr)) * 512 + h * 128;
      #pragma unroll
      for (int c = 0; c < 8; ++c) op[c * 16 + l16] = f2bf(o_acc[c][r] * linv[r]);
    }
  }
}

// ---------------- layernorm (+ optional bf16 copy) ----------------
__global__ __launch_bounds__(256) void ln_kernel(
    const float* __restrict__ x, const float* __restrict__ res,
    const float* __restrict__ g, const float* __restrict__ bta,
    const float* __restrict__ npm, float* __restrict__ out,
    unsigned short* __restrict__ out16) {
  __shared__ float ssum[4], ssq[4];
  int row = blockIdx.x;
  int tid = threadIdx.x;
  size_t base = (size_t)row * DM_;
  float v0 = x[base + tid] + res[base + tid];
  float v1 = x[base + tid + 256] + res[base + tid + 256];
  float sum = v0 + v1, sq = v0 * v0 + v1 * v1;
  #pragma unroll
  for (int off = 32; off >= 1; off >>= 1) {
    sum += __shfl_down(sum, off);
    sq += __shfl_down(sq, off);
  }
  int wid = tid >> 6, lane = tid & 63;
  if (lane == 0) { ssum[wid] = sum; ssq[wid] = sq; }
  __syncthreads();
  sum = ssum[0] + ssum[1] + ssum[2] + ssum[3];
  sq = ssq[0] + ssq[1] + ssq[2] + ssq[3];
  float mean = sum * (1.f / DM_);
  float var = sq * (1.f / DM_) - mean * mean;
  float rs = rsqrtf(var + 1e-5f);
  float mask = npm[row];
  float o0 = ((v0 - mean) * rs * g[tid] + bta[tid]) * mask;
  float o1 = ((v1 - mean) * rs * g[tid + 256] + bta[tid + 256]) * mask;
  out[base + tid] = o0;
  out[base + tid + 256] = o1;
  if (out16) {
    out16[base + tid] = f2bf(o0);
    out16[base + tid + 256] = f2bf(o1);
  }
}

extern "C" void kernel_launch(void* const* d_in, const int* in_sizes, int n_in,
                              void* d_out, int out_size, void* d_ws,
                              size_t ws_size, hipStream_t stream) {
  const int* et = (const int*)d_in[0];
  const int* vx = (const int*)d_in[1];
  const float* tmv = (const float*)d_in[2];
  const float* npm = (const float*)d_in[3];
  const float* Amat = (const float*)d_in[4];
  const float* Wmat = (const float*)d_in[5];
  const float* eemb = (const float*)d_in[6];
  const float* vemb = (const float*)d_in[7];
  const float* Wq = (const float*)d_in[8];
  const float* Wk = (const float*)d_in[9];
  const float* Wv = (const float*)d_in[10];
  const float* Wo = (const float*)d_in[11];
  const float* bo = (const float*)d_in[12];
  const float* ln1g = (const float*)d_in[13];
  const float* ln1b = (const float*)d_in[14];
  const float* w1 = (const float*)d_in[15];
  const float* b1 = (const float*)d_in[16];
  const float* w2 = (const float*)d_in[17];
  const float* b2 = (const float*)d_in[18];
  const float* ln2g = (const float*)d_in[19];
  const float* ln2b = (const float*)d_in[20];

  float* out = (float*)d_out;
  float* enc_out = out;
  float* sim_out = out + (size_t)B_ * S_ * DM_;

  const size_t MB = 1ull << 20;
  char* wsb = (char*)d_ws;
  float* enc0 = (float*)(wsb + 0);                             // 16MB, live to LN1
  unsigned short* enc0b = (unsigned short*)(wsb + 16 * MB);    // 8MB
  unsigned short* WqT = (unsigned short*)(wsb + 24 * MB);
  unsigned short* WkT = WqT + 512 * 512;
  unsigned short* WvT = WkT + 512 * 512;
  unsigned short* WoT = WvT + 512 * 512;
  unsigned short* w1T = WoT + 512 * 512;
  unsigned short* w2T = w1T + 1024 * 512;
  unsigned short* Qb16 = (unsigned short*)(wsb + 28 * MB);
  unsigned short* Kb16 = (unsigned short*)(wsb + 36 * MB);
  unsigned short* Vt16 = (unsigned short*)(wsb + 44 * MB);
  unsigned short* Of16 = (unsigned short*)(wsb + 52 * MB);
  float* OP = (float*)(wsb + 60 * MB);
  float* enc1 = OP;
  unsigned short* enc1b = (unsigned short*)(wsb + 16 * MB);
  unsigned short* hid = (unsigned short*)(wsb + 28 * MB);
  float* fbuf = (float*)(wsb + 44 * MB);

  int M = B_ * S_;

  embed_kernel<<<dim3(M), dim3(256), 0, stream>>>(et, vx, tmv, npm, eemb, vemb,
                                                  enc0, enc0b);
  sim_kernel<<<dim3(S_, B_), dim3(256), 0, stream>>>(vx, Amat, Wmat, sim_out);

  wt_kernel<<<dim3(16, 16), dim3(256), 0, stream>>>(Wq, WqT, 512, 512);
  wt_kernel<<<dim3(16, 16), dim3(256), 0, stream>>>(Wk, WkT, 512, 512);
  wt_kernel<<<dim3(16, 16), dim3(256), 0, stream>>>(Wv, WvT, 512, 512);
  wt_kernel<<<dim3(16, 16), dim3(256), 0, stream>>>(Wo, WoT, 512, 512);
  wt_kernel<<<dim3(32, 16), dim3(256), 0, stream>>>(w1, w1T, 512, 1024);
  wt_kernel<<<dim3(16, 32), dim3(256), 0, stream>>>(w2, w2T, 1024, 512);

  gemm_bf16_kernel<2, false><<<dim3(4, 64), dim3(256), 0, stream>>>(
      enc0b, WqT, nullptr, Qb16, M, DM_, DM_);
  gemm_bf16_kernel<2, false><<<dim3(4, 64), dim3(256), 0, stream>>>(
      enc0b, WkT, nullptr, Kb16, M, DM_, DM_);
  gemm_bf16_kernel<3, false><<<dim3(4, 64), dim3(256), 0, stream>>>(
      enc0b, WvT, nullptr, Vt16, M, DM_, DM_);

  attn_mfma_kernel<<<dim3(32, 16), dim3(128), 0, stream>>>(
      Qb16, Kb16, Vt16, sim_out, npm, Of16);

  gemm_bf16_kernel<0, false><<<dim3(4, 64), dim3(256), 0, stream>>>(
      Of16, WoT, bo, OP, M, DM_, DM_);
  ln_kernel<<<dim3(M), dim3(256), 0, stream>>>(OP, enc0, ln1g, ln1b, npm, enc1,
                                               enc1b);

  gemm_bf16_kernel<1, true><<<dim3(8, 64), dim3(256), 0, stream>>>(
      enc1b, w1T, b1, hid, M, DI_, DM_);
  gemm_bf16_kernel<0, false><<<dim3(4, 64), dim3(256), 0, stream>>>(
      hid, w2T, b2, fbuf, M, DM_, DI_);
  ln_kernel<<<dim3(M), dim3(256), 0, stream>>>(fbuf, enc1, ln2g, ln2b, npm,
                                               enc_out, nullptr);
}

// Round 11
// 400.010 us; speedup vs baseline: 1.3672x; 1.3672x over previous
//
#include <hip/hip_runtime.h>
#include <hip/hip_bf16.h>

#define B_ 4
#define S_ 2048
#define DM_ 512
#define H_ 4
#define DK_ 128
#define DI_ 1024
#define NV_ 5000

typedef __attribute__((ext_vector_type(8))) short bf16x8;
typedef __attribute__((ext_vector_type(8))) unsigned short u16x8;
typedef __attribute__((ext_vector_type(4))) unsigned short u16x4;
typedef __attribute__((ext_vector_type(4))) float f32x4;

__device__ inline unsigned short f2bf(float x) {
  unsigned int u = __float_as_uint(x);
  unsigned int r = (u + 0x7fffu + ((u >> 16) & 1u)) >> 16;
  return (unsigned short)r;
}
__device__ inline float bf2f(unsigned short u) {
  return __uint_as_float(((unsigned int)u) << 16);
}

// ---------------- embed + temporal (f32 + bf16 outputs) ----------------
__global__ __launch_bounds__(256) void embed_kernel(
    const int* __restrict__ et, const int* __restrict__ vx,
    const float* __restrict__ tmv, const float* __restrict__ npm,
    const float* __restrict__ eemb, const float* __restrict__ vemb,
    float* __restrict__ enc0, unsigned short* __restrict__ enc0b) {
  int row = blockIdx.x;
  int t = et[row], v = vx[row];
  float time = tmv[row], mask = npm[row];
  int tid = threadIdx.x;
  #pragma unroll
  for (int k = 0; k < 2; ++k) {
    int dd = tid + k * 256;
    float pv = powf(10000.0f, (float)(dd & ~1) / 512.0f);
    float r = time / pv;
    float tem = (((dd & 1) == 0) ? sinf(r) : cosf(r)) * mask;
    float val = eemb[(size_t)t * DM_ + dd] + vemb[(size_t)v * DM_ + dd] + tem;
    enc0[(size_t)row * DM_ + dd] = val;
    enc0b[(size_t)row * DM_ + dd] = f2bf(val);
  }
}

// ---------------- similarity: stage A,W rows in LDS, gather ----------------
__global__ __launch_bounds__(256) void sim_kernel(
    const int* __restrict__ vx, const float* __restrict__ A,
    const float* __restrict__ W, float* __restrict__ sim) {
  __shared__ float Ar[NV_];
  __shared__ float Wr[NV_];
  int i = blockIdx.x;
  int b = blockIdx.y;
  int vi = vx[b * S_ + i];
  float* out = sim + ((size_t)(b * S_ + i)) * S_;
  int tid = threadIdx.x;
  if (vi == 0) {
    for (int j = tid * 4; j < S_; j += 1024)
      *(float4*)&out[j] = (float4){0.f, 0.f, 0.f, 0.f};
    return;
  }
  const float4* Arow = (const float4*)(A + (size_t)(vi - 1) * NV_);
  const float4* Wrow = (const float4*)(W + (size_t)(vi - 1) * NV_);
  for (int j = tid; j < NV_ / 4; j += 256) {
    ((float4*)Ar)[j] = Arow[j];
    ((float4*)Wr)[j] = Wrow[j];
  }
  __syncthreads();
  for (int j = tid * 4; j < S_; j += 1024) {
    int4 vj = *(const int4*)&vx[b * S_ + j];
    float4 o;
    o.x = vj.x ? Ar[vj.x - 1] * Wr[vj.x - 1] * 10.0f : 0.f;
    o.y = vj.y ? Ar[vj.y - 1] * Wr[vj.y - 1] * 10.0f : 0.f;
    o.z = vj.z ? Ar[vj.z - 1] * Wr[vj.z - 1] * 10.0f : 0.f;
    o.w = vj.w ? Ar[vj.w - 1] * Wr[vj.w - 1] * 10.0f : 0.f;
    *(float4*)&out[j] = o;
  }
}

// ---------------- weight transpose+cast: W[K][N] f32 -> WT[N][K] bf16 ----------------
__global__ __launch_bounds__(256) void wt_kernel(
    const float* __restrict__ W, unsigned short* __restrict__ WT,
    int K, int N) {
  __shared__ unsigned short T[32][40];
  int n0 = blockIdx.x * 32, k0 = blockIdx.y * 32;
  int r = threadIdx.x >> 3, c0 = (threadIdx.x & 7) * 4;
  float4 v = *(const float4*)&W[(size_t)(k0 + r) * N + n0 + c0];
  T[r][c0 + 0] = f2bf(v.x);
  T[r][c0 + 1] = f2bf(v.y);
  T[r][c0 + 2] = f2bf(v.z);
  T[r][c0 + 3] = f2bf(v.w);
  __syncthreads();
  u16x4 o;
  o[0] = T[c0 + 0][r]; o[1] = T[c0 + 1][r];
  o[2] = T[c0 + 2][r]; o[3] = T[c0 + 3][r];
  *(u16x4*)&WT[(size_t)(n0 + r) * K + k0 + c0] = o;
}

// ---------------- bf16 MFMA GEMM: C = A[M,K] @ BT[N,K]^T (+bias)(+relu) ----------------
// OMODE: 0 = f32 [M][N]; 1 = bf16 [M][N]; 5 = fused QKV (Q/K head-split, V transposed)
template <int OMODE, bool RELU>
__global__ __launch_bounds__(256) void gemm_bf16_kernel(
    const unsigned short* __restrict__ A, const unsigned short* __restrict__ BT,
    const float* __restrict__ bias, void* __restrict__ C,
    int M, int N, int K) {
  __shared__ __attribute__((aligned(16))) unsigned short As[128][72];
  __shared__ __attribute__((aligned(16))) unsigned short Bs[128][72];
  int tid = threadIdx.x;
  int w = tid >> 6, l = tid & 63;
  int l16 = l & 15, lh = l >> 4;
  int wr = w >> 1, wc = w & 1;
  int row0 = blockIdx.y * 128, col0 = blockIdx.x * 128;
  int ra = tid >> 1, ha = (tid & 1) * 32;
  f32x4 acc[4][4];
  #pragma unroll
  for (int m = 0; m < 4; ++m)
    #pragma unroll
    for (int n = 0; n < 4; ++n) acc[m][n] = (f32x4){0.f, 0.f, 0.f, 0.f};

  for (int k0 = 0; k0 < K; k0 += 64) {
    __syncthreads();
    {
      const unsigned short* sa = &A[(size_t)(row0 + ra) * K + k0 + ha];
      uint4 a0 = *(const uint4*)(sa);
      uint4 a1 = *(const uint4*)(sa + 8);
      uint4 a2 = *(const uint4*)(sa + 16);
      uint4 a3 = *(const uint4*)(sa + 24);
      *(uint4*)&As[ra][ha + 0] = a0;
      *(uint4*)&As[ra][ha + 8] = a1;
      *(uint4*)&As[ra][ha + 16] = a2;
      *(uint4*)&As[ra][ha + 24] = a3;
      const unsigned short* sb = &BT[(size_t)(col0 + ra) * K + k0 + ha];
      uint4 b0 = *(const uint4*)(sb);
      uint4 b1 = *(const uint4*)(sb + 8);
      uint4 b2 = *(const uint4*)(sb + 16);
      uint4 b3 = *(const uint4*)(sb + 24);
      *(uint4*)&Bs[ra][ha + 0] = b0;
      *(uint4*)&Bs[ra][ha + 8] = b1;
      *(uint4*)&Bs[ra][ha + 16] = b2;
      *(uint4*)&Bs[ra][ha + 24] = b3;
    }
    __syncthreads();
    #pragma unroll
    for (int kc = 0; kc < 2; ++kc) {
      bf16x8 af[4], bfr[4];
      #pragma unroll
      for (int m = 0; m < 4; ++m)
        af[m] = *(bf16x8*)&As[wr * 64 + m * 16 + l16][kc * 32 + lh * 8];
      #pragma unroll
      for (int n = 0; n < 4; ++n)
        bfr[n] = *(bf16x8*)&Bs[wc * 64 + n * 16 + l16][kc * 32 + lh * 8];
      #pragma unroll
      for (int m = 0; m < 4; ++m)
        #pragma unroll
        for (int n = 0; n < 4; ++n)
          acc[m][n] = __builtin_amdgcn_mfma_f32_16x16x32_bf16(af[m], bfr[n], acc[m][n], 0, 0, 0);
    }
  }
  #pragma unroll
  for (int m = 0; m < 4; ++m) {
    #pragma unroll
    for (int r = 0; r < 4; ++r) {
      int row = row0 + wr * 64 + m * 16 + lh * 4 + r;
      #pragma unroll
      for (int n = 0; n < 4; ++n) {
        int colg = col0 + wc * 64 + n * 16 + l16;
        float v = acc[m][n][r];
        if (bias) v += bias[colg];
        if (RELU) v = fmaxf(v, 0.f);
        if (OMODE == 0) {
          ((float*)C)[(size_t)row * N + colg] = v;
        } else if (OMODE == 1) {
          ((unsigned short*)C)[(size_t)row * N + colg] = f2bf(v);
        } else {  // OMODE 5: fused QKV epilogue
          int which = colg >> 9;       // 0=Q 1=K 2=V
          int cl = colg & 511;
          int b = row >> 11, s = row & 2047;
          int h = cl >> 7, d = cl & 127;
          unsigned short* base =
              (unsigned short*)C + (size_t)which * (4194304);
          if (which < 2)
            base[((size_t)((b * 4 + h) * 2048 + s)) * 128 + d] = f2bf(v);
          else
            base[((size_t)((b * 4 + h) * 128 + d)) * 2048 + s] = f2bf(v);
        }
      }
    }
  }
}

// ---------------- MFMA flash attention partial: paired q-tiles + KV split -------
// grid = (16 pairs, 16 bh, 2 halves); block = 256 (4 waves); ~16.5 steps/block.
__global__ __launch_bounds__(256) void attn_mfma_kernel(
    const unsigned short* __restrict__ Qb, const unsigned short* __restrict__ Kb,
    const unsigned short* __restrict__ Vt, const float* __restrict__ sim,
    const float* __restrict__ npm, unsigned short* __restrict__ Op0,
    unsigned short* __restrict__ Op1, float2* __restrict__ ml0,
    float2* __restrict__ ml1) {
  __shared__ __attribute__((aligned(16))) unsigned short Ks[64][136];
  __shared__ __attribute__((aligned(16))) unsigned short Vts[128][72];
  __shared__ __attribute__((aligned(16))) unsigned short Pl[4][16][72];
  int pair = blockIdx.x;   // 0..15
  int bh = blockIdx.y;     // b*H + h
  int half = blockIdx.z;   // KV half
  int b = bh >> 2;
  int tid = threadIdx.x;
  int w = tid >> 6, l = tid & 63;
  int l16 = l & 15, lh = l >> 4;
  int kr = tid >> 4, kc = tid & 15;
  int vr = tid >> 3, vc = tid & 7;
  unsigned short* Op = half ? Op1 : Op0;
  float2* ml = half ? ml1 : ml0;

  uint4 kg[4], vg[4];
  auto stage_load = [&](int kv0) {
    const unsigned short* kp = Kb + ((size_t)(bh * 2048 + kv0 + kr)) * 128 + kc * 8;
    kg[0] = *(const uint4*)(kp);
    kg[1] = *(const uint4*)(kp + 16 * 128);
    kg[2] = *(const uint4*)(kp + 32 * 128);
    kg[3] = *(const uint4*)(kp + 48 * 128);
    const unsigned short* vp = Vt + ((size_t)(bh * 128 + vr)) * 2048 + kv0 + vc * 8;
    vg[0] = *(const uint4*)(vp);
    vg[1] = *(const uint4*)(vp + 32 * 2048);
    vg[2] = *(const uint4*)(vp + 64 * 2048);
    vg[3] = *(const uint4*)(vp + 96 * 2048);
  };
  auto stage_write = [&]() {
    *(uint4*)&Ks[kr][kc * 8] = kg[0];
    *(uint4*)&Ks[kr + 16][kc * 8] = kg[1];
    *(uint4*)&Ks[kr + 32][kc * 8] = kg[2];
    *(uint4*)&Ks[kr + 48][kc * 8] = kg[3];
    *(uint4*)&Vts[vr][vc * 8] = vg[0];
    *(uint4*)&Vts[vr + 32][vc * 8] = vg[1];
    *(uint4*)&Vts[vr + 64][vc * 8] = vg[2];
    *(uint4*)&Vts[vr + 96][vc * 8] = vg[3];
  };

  #pragma unroll 1
  for (int pi = 0; pi < 2; ++pi) {
    int qt = pi ? 31 - pair : pair;
    int n = qt + 1;                 // total kv tiles for this q tile
    int c0 = (n + 1) >> 1;          // half0 count (ceil)
    int t0 = half ? c0 : 0;
    int cnt = half ? (n - c0) : c0;
    int q0 = qt * 64 + w * 16;
    int qg = q0 + l16;              // this lane's q row (swapped layout)

    bf16x8 qf[4];
    const unsigned short* Qrow = Qb + ((size_t)(bh * 2048 + qg)) * 128;
    #pragma unroll
    for (int kq = 0; kq < 4; ++kq)
      qf[kq] = *(const bf16x8*)&Qrow[kq * 32 + lh * 8];

    float m_l = -INFINITY, l_l = 0.f;
    f32x4 o_acc[8];
    #pragma unroll
    for (int c = 0; c < 8; ++c) o_acc[c] = (f32x4){0.f, 0.f, 0.f, 0.f};

    if (cnt > 0) {
      stage_load(t0 * 64);
      stage_write();
      __syncthreads();

      #pragma unroll 1
      for (int ti = 0; ti < cnt; ++ti) {
        int t = t0 + ti;
        int kv0 = t * 64;
        if (ti + 1 < cnt) stage_load(kv0 + 64);

        float simv[4][4];
        float4 mk4[4];
        #pragma unroll
        for (int tt = 0; tt < 4; ++tt) {
          mk4[tt] = *(const float4*)&npm[b * 2048 + kv0 + tt * 16 + lh * 4];
          #pragma unroll
          for (int r = 0; r < 4; ++r)
            simv[tt][r] =
                sim[((size_t)(b * 2048) + qg) * 2048 + kv0 + tt * 16 + lh * 4 + r];
        }

        f32x4 sc[4];
        #pragma unroll
        for (int tt = 0; tt < 4; ++tt) {
          sc[tt] = (f32x4){0.f, 0.f, 0.f, 0.f};
          #pragma unroll
          for (int kq = 0; kq < 4; ++kq) {
            bf16x8 kf = *(bf16x8*)&Ks[tt * 16 + l16][kq * 32 + lh * 8];
            sc[tt] = __builtin_amdgcn_mfma_f32_16x16x32_bf16(kf, qf[kq], sc[tt], 0, 0, 0);
          }
        }
        float sv[4][4];
        #pragma unroll
        for (int tt = 0; tt < 4; ++tt) {
          #pragma unroll
          for (int r = 0; r < 4; ++r) {
            int kvg = kv0 + tt * 16 + lh * 4 + r;
            float mkr = r == 0 ? mk4[tt].x : r == 1 ? mk4[tt].y : r == 2 ? mk4[tt].z : mk4[tt].w;
            bool valid = (kvg <= qg) && (mkr != 0.f);
            sv[tt][r] = valid ? sc[tt][r] * 0.08838834764831845f + simv[tt][r]
                              : -1e9f;
          }
        }
        float mx = sv[0][0];
        #pragma unroll
        for (int tt = 0; tt < 4; ++tt)
          #pragma unroll
          for (int r = 0; r < 4; ++r) mx = fmaxf(mx, sv[tt][r]);
        mx = fmaxf(mx, __shfl_xor(mx, 16));
        mx = fmaxf(mx, __shfl_xor(mx, 32));
        float mn = fmaxf(m_l, mx);
        float alpha = __expf(m_l - mn);
        m_l = mn;
        float ts = 0.f;
        #pragma unroll
        for (int tt = 0; tt < 4; ++tt)
          #pragma unroll
          for (int r = 0; r < 4; ++r) {
            float p = __expf(sv[tt][r] - mn);
            sv[tt][r] = p;
            ts += p;
          }
        ts += __shfl_xor(ts, 16);
        ts += __shfl_xor(ts, 32);
        l_l = l_l * alpha + ts;
        #pragma unroll
        for (int tt = 0; tt < 4; ++tt) {
          u16x4 pw;
          pw[0] = f2bf(sv[tt][0]); pw[1] = f2bf(sv[tt][1]);
          pw[2] = f2bf(sv[tt][2]); pw[3] = f2bf(sv[tt][3]);
          *(u16x4*)&Pl[w][l16][tt * 16 + lh * 4] = pw;
        }
        float al[4];
        #pragma unroll
        for (int r = 0; r < 4; ++r) al[r] = __shfl(alpha, lh * 4 + r);
        #pragma unroll
        for (int c = 0; c < 8; ++c)
          #pragma unroll
          for (int r = 0; r < 4; ++r) o_acc[c][r] *= al[r];
        #pragma unroll
        for (int kf2 = 0; kf2 < 2; ++kf2) {
          bf16x8 pa = *(bf16x8*)&Pl[w][l16][kf2 * 32 + lh * 8];
          #pragma unroll
          for (int c = 0; c < 8; ++c) {
            bf16x8 vf = *(bf16x8*)&Vts[c * 16 + l16][kf2 * 32 + lh * 8];
            o_acc[c] = __builtin_amdgcn_mfma_f32_16x16x32_bf16(pa, vf, o_acc[c], 0, 0, 0);
          }
        }
        __syncthreads();
        if (ti + 1 < cnt) {
          stage_write();
          __syncthreads();
        }
      }
    }
    // epilogue: write unnormalized partial O (bf16) + (m, l)
    #pragma unroll
    for (int r = 0; r < 4; ++r) {
      int qgr = q0 + lh * 4 + r;
      unsigned short* op = Op + ((size_t)(bh * 2048 + qgr)) * 128;
      #pragma unroll
      for (int c = 0; c < 8; ++c) op[c * 16 + l16] = f2bf(o_acc[c][r]);
    }
    if (lh == 0) {
      float2 v; v.x = m_l; v.y = l_l;
      ml[bh * 2048 + q0 + l16] = v;
    }
    __syncthreads();
  }
}

// ---------------- combine partials -> final attn output (token-major bf16) ------
__global__ __launch_bounds__(256) void attn_combine_kernel(
    const unsigned short* __restrict__ Op0, const unsigned short* __restrict__ Op1,
    const float2* __restrict__ ml0, const float2* __restrict__ ml1,
    unsigned short* __restrict__ Of) {
  int idx = blockIdx.x * 256 + threadIdx.x;  // 524288 threads
  int row = idx >> 4;          // bh*2048 + q
  int d0 = (idx & 15) * 8;
  float2 a = ml0[row], c2 = ml1[row];
  float m = fmaxf(a.x, c2.x);
  float e1 = __expf(a.x - m), e2 = __expf(c2.x - m);
  float inv = 1.f / (e1 * a.y + e2 * c2.y);
  u16x8 o1 = *(const u16x8*)&Op0[(size_t)row * 128 + d0];
  u16x8 o2 = *(const u16x8*)&Op1[(size_t)row * 128 + d0];
  int bh = row >> 11, q = row & 2047;
  int b = bh >> 2, h = bh & 3;
  unsigned short* dst = Of + ((size_t)(b * 2048 + q)) * 512 + h * 128 + d0;
  u16x8 o;
  #pragma unroll
  for (int j = 0; j < 8; ++j)
    o[j] = f2bf((bf2f(o1[j]) * e1 + bf2f(o2[j]) * e2) * inv);
  *(u16x8*)dst = o;
}

// ---------------- layernorm (+ optional bf16 copy) ----------------
__global__ __launch_bounds__(256) void ln_kernel(
    const float* __restrict__ x, const float* __restrict__ res,
    const float* __restrict__ g, const float* __restrict__ bta,
    const float* __restrict__ npm, float* __restrict__ out,
    unsigned short* __restrict__ out16) {
  __shared__ float ssum[4], ssq[4];
  int row = blockIdx.x;
  int tid = threadIdx.x;
  size_t base = (size_t)row * DM_;
  float v0 = x[base + tid] + res[base + tid];
  float v1 = x[base + tid + 256] + res[base + tid + 256];
  float sum = v0 + v1, sq = v0 * v0 + v1 * v1;
  #pragma unroll
  for (int off = 32; off >= 1; off >>= 1) {
    sum += __shfl_down(sum, off);
    sq += __shfl_down(sq, off);
  }
  int wid = tid >> 6, lane = tid & 63;
  if (lane == 0) { ssum[wid] = sum; ssq[wid] = sq; }
  __syncthreads();
  sum = ssum[0] + ssum[1] + ssum[2] + ssum[3];
  sq = ssq[0] + ssq[1] + ssq[2] + ssq[3];
  float mean = sum * (1.f / DM_);
  float var = sq * (1.f / DM_) - mean * mean;
  float rs = rsqrtf(var + 1e-5f);
  float mask = npm[row];
  float o0 = ((v0 - mean) * rs * g[tid] + bta[tid]) * mask;
  float o1 = ((v1 - mean) * rs * g[tid + 256] + bta[tid + 256]) * mask;
  out[base + tid] = o0;
  out[base + tid + 256] = o1;
  if (out16) {
    out16[base + tid] = f2bf(o0);
    out16[base + tid + 256] = f2bf(o1);
  }
}

extern "C" void kernel_launch(void* const* d_in, const int* in_sizes, int n_in,
                              void* d_out, int out_size, void* d_ws,
                              size_t ws_size, hipStream_t stream) {
  const int* et = (const int*)d_in[0];
  const int* vx = (const int*)d_in[1];
  const float* tmv = (const float*)d_in[2];
  const float* npm = (const float*)d_in[3];
  const float* Amat = (const float*)d_in[4];
  const float* Wmat = (const float*)d_in[5];
  const float* eemb = (const float*)d_in[6];
  const float* vemb = (const float*)d_in[7];
  const float* Wq = (const float*)d_in[8];
  const float* Wk = (const float*)d_in[9];
  const float* Wv = (const float*)d_in[10];
  const float* Wo = (const float*)d_in[11];
  const float* bo = (const float*)d_in[12];
  const float* ln1g = (const float*)d_in[13];
  const float* ln1b = (const float*)d_in[14];
  const float* w1 = (const float*)d_in[15];
  const float* b1 = (const float*)d_in[16];
  const float* w2 = (const float*)d_in[17];
  const float* b2 = (const float*)d_in[18];
  const float* ln2g = (const float*)d_in[19];
  const float* ln2b = (const float*)d_in[20];

  float* out = (float*)d_out;
  float* enc_out = out;
  float* sim_out = out + (size_t)B_ * S_ * DM_;

  const size_t MB = 1ull << 20;
  char* wsb = (char*)d_ws;
  float* enc0 = (float*)(wsb + 0);                             // 16MB, live to LN1
  unsigned short* enc0b = (unsigned short*)(wsb + 16 * MB);    // 8MB (dead after QKV)
  unsigned short* WqT = (unsigned short*)(wsb + 24 * MB);      // QKV contiguous 1.5MB
  unsigned short* WkT = WqT + 512 * 512;
  unsigned short* WvT = WkT + 512 * 512;
  unsigned short* WoT = WvT + 512 * 512;
  unsigned short* w1T = WoT + 512 * 512;                       // ends 27MB
  unsigned short* w2T = w1T + 1024 * 512;                      // ends 28MB
  unsigned short* Qb16 = (unsigned short*)(wsb + 28 * MB);     // 8MB
  unsigned short* Kb16 = (unsigned short*)(wsb + 36 * MB);     // 8MB
  unsigned short* Vt16 = (unsigned short*)(wsb + 44 * MB);     // 8MB
  unsigned short* Op0 = (unsigned short*)(wsb + 52 * MB);      // 8MB partial half0
  unsigned short* Op1 = enc0b;                                 // 8MB partial half1
  float2* ml0 = (float2*)(wsb + 60 * MB);                      // 256KB
  float2* ml1 = ml0 + 32768;                                   // 256KB
  unsigned short* Of16 = Qb16;          // final attn out (Qb16 dead post-attn)
  float* OP = (float*)(wsb + 60 * MB);  // Wo out (ml dead by then)
  float* enc1 = OP;
  unsigned short* enc1b = enc0b;        // LN1 bf16 (Op1 dead post-combine)
  unsigned short* hid = Kb16;           // FFN hidden 16MB over Kb16+Vt16
  float* fbuf = (float*)(wsb + 44 * MB);  // unused slot? Vt16 region overlaps hid!

  // fix: hid spans 36-52MB (Kb16+Vt16); fbuf must not overlap hid or enc1.
  fbuf = (float*)(wsb + 76 * MB);  // 16MB at 76-92MB (ws is large; used before)

  int M = B_ * S_;

  embed_kernel<<<dim3(M), dim3(256), 0, stream>>>(et, vx, tmv, npm, eemb, vemb,
                                                  enc0, enc0b);
  sim_kernel<<<dim3(S_, B_), dim3(256), 0, stream>>>(vx, Amat, Wmat, sim_out);

  wt_kernel<<<dim3(16, 16), dim3(256), 0, stream>>>(Wq, WqT, 512, 512);
  wt_kernel<<<dim3(16, 16), dim3(256), 0, stream>>>(Wk, WkT, 512, 512);
  wt_kernel<<<dim3(16, 16), dim3(256), 0, stream>>>(Wv, WvT, 512, 512);
  wt_kernel<<<dim3(16, 16), dim3(256), 0, stream>>>(Wo, WoT, 512, 512);
  wt_kernel<<<dim3(32, 16), dim3(256), 0, stream>>>(w1, w1T, 512, 1024);
  wt_kernel<<<dim3(16, 32), dim3(256), 0, stream>>>(w2, w2T, 1024, 512);

  // fused QKV GEMM: BT = [WqT; WkT; WvT] contiguous (N = 1536)
  gemm_bf16_kernel<5, false><<<dim3(12, 64), dim3(256), 0, stream>>>(
      enc0b, WqT, nullptr, Qb16, M, 3 * DM_, DM_);

  attn_mfma_kernel<<<dim3(16, 16, 2), dim3(256), 0, stream>>>(
      Qb16, Kb16, Vt16, sim_out, npm, Op0, Op1, ml0, ml1);
  attn_combine_kernel<<<dim3(2048), dim3(256), 0, stream>>>(
      Op0, Op1, ml0, ml1, Of16);

  gemm_bf16_kernel<0, false><<<dim3(4, 64), dim3(256), 0, stream>>>(
      Of16, WoT, bo, OP, M, DM_, DM_);
  ln_kernel<<<dim3(M), dim3(256), 0, stream>>>(OP, enc0, ln1g, ln1b, npm, enc1,
                                               enc1b);

  gemm_bf16_kernel<1, true><<<dim3(8, 64), dim3(256), 0, stream>>>(
      enc1b, w1T, b1, hid, M, DI_, DM_);
  gemm_bf16_kernel<0, false><<<dim3(4, 64), dim3(256), 0, stream>>>(
      hid, w2T, b2, fbuf, M, DM_, DI_);
  ln_kernel<<<dim3(M), dim3(256), 0, stream>>>(fbuf, enc1, ln2g, ln2b, npm,
                                               enc_out, nullptr);
}